// Round 1
// baseline (752.941 us; speedup 1.0000x reference)
//
#include <hip/hip_runtime.h>

// ---------------- problem constants ----------------
constexpr int BB = 1024;      // batch
constexpr int DD = 2048;      // feature dim
constexpr int NN = 16384;     // memory entries
constexpr float TEMP   = 0.05f;
constexpr float LAMBDA2 = 0.5f;
constexpr float MU      = 1.0f;
constexpr float EPSN    = 1e-12f;

typedef __bf16  bf16x8  __attribute__((ext_vector_type(8)));
typedef unsigned short ushort8 __attribute__((ext_vector_type(8)));
typedef float   floatx4 __attribute__((ext_vector_type(4)));

__device__ inline unsigned short f32_to_bf16(float f) {
  unsigned int u = __builtin_bit_cast(unsigned int, f);
  u += 0x7fffu + ((u >> 16) & 1u);      // round-to-nearest-even
  return (unsigned short)(u >> 16);
}

__device__ inline float block_sum256(float v, float* sbuf) {
#pragma unroll
  for (int o = 32; o > 0; o >>= 1) v += __shfl_down(v, o, 64);
  int lane = threadIdx.x & 63, w = threadIdx.x >> 6;
  __syncthreads();
  if (lane == 0) sbuf[w] = v;
  __syncthreads();
  return sbuf[0] + sbuf[1] + sbuf[2] + sbuf[3];
}

__device__ inline float block_max256(float v, float* sbuf) {
#pragma unroll
  for (int o = 32; o > 0; o >>= 1) v = fmaxf(v, __shfl_down(v, o, 64));
  int lane = threadIdx.x & 63, w = threadIdx.x >> 6;
  __syncthreads();
  if (lane == 0) sbuf[w] = v;
  __syncthreads();
  return fmaxf(fmaxf(sbuf[0], sbuf[1]), fmaxf(sbuf[2], sbuf[3]));
}

// ---------------- K1: row-l2norm of student -> bf16, MSE vs normalized teacher ----
__global__ void __launch_bounds__(256) norm_mse_kernel(
    const float* __restrict__ X, const float* __restrict__ T,
    unsigned short* __restrict__ Xb, float* __restrict__ mse_part) {
  __shared__ float sbuf[4];
  const int b = blockIdx.x;
  const float4* xr = (const float4*)(X + (size_t)b * DD);
  const float4* tr = (const float4*)(T + (size_t)b * DD);
  float4 xv[2], tv[2];
  float sx = 0.f, st = 0.f;
#pragma unroll
  for (int i = 0; i < 2; ++i) {
    int idx = i * 256 + threadIdx.x;      // DD/4 = 512
    xv[i] = xr[idx];  tv[i] = tr[idx];
    sx += xv[i].x*xv[i].x + xv[i].y*xv[i].y + xv[i].z*xv[i].z + xv[i].w*xv[i].w;
    st += tv[i].x*tv[i].x + tv[i].y*tv[i].y + tv[i].z*tv[i].z + tv[i].w*tv[i].w;
  }
  sx = block_sum256(sx, sbuf);
  st = block_sum256(st, sbuf);
  const float rx = 1.f / fmaxf(sqrtf(sx), EPSN);
  const float rt = 1.f / fmaxf(sqrtf(st), EPSN);
  float ms = 0.f;
  ushort4* xb4 = (ushort4*)(Xb + (size_t)b * DD);
#pragma unroll
  for (int i = 0; i < 2; ++i) {
    int idx = i * 256 + threadIdx.x;
    float xn, tn, d;
    ushort4 o;
    xn = xv[i].x * rx; tn = tv[i].x * rt; d = xn - tn; ms += d * d; o.x = f32_to_bf16(xn);
    xn = xv[i].y * rx; tn = tv[i].y * rt; d = xn - tn; ms += d * d; o.y = f32_to_bf16(xn);
    xn = xv[i].z * rx; tn = tv[i].z * rt; d = xn - tn; ms += d * d; o.z = f32_to_bf16(xn);
    xn = xv[i].w * rx; tn = tv[i].w * rt; d = xn - tn; ms += d * d; o.w = f32_to_bf16(xn);
    xb4[idx] = o;
  }
  ms = block_sum256(ms, sbuf);
  if (threadIdx.x == 0) mse_part[b] = ms;
}

// ---------------- K2: features fp32 -> bf16, pure streaming convert ----------------
__global__ void __launch_bounds__(256) feat_convert_kernel(
    const float* __restrict__ F, unsigned short* __restrict__ Fb) {
  const int stride = gridDim.x * 256;
  const float4* fr = (const float4*)F;
  constexpr int TOT = NN * DD / 8;            // ushort8 chunks
  for (int i = blockIdx.x * 256 + threadIdx.x; i < TOT; i += stride) {
    float4 a = fr[i * 2], b = fr[i * 2 + 1];
    ushort8 o;
    o[0] = f32_to_bf16(a.x); o[1] = f32_to_bf16(a.y);
    o[2] = f32_to_bf16(a.z); o[3] = f32_to_bf16(a.w);
    o[4] = f32_to_bf16(b.x); o[5] = f32_to_bf16(b.y);
    o[6] = f32_to_bf16(b.z); o[7] = f32_to_bf16(b.w);
    *(ushort8*)(Fb + (size_t)i * 8) = o;
  }
}

// ---------------- K3: bf16 MFMA GEMM  sim[M,N] = A[M,K] * Bm[N,K]^T ---------------
// 256x256 tile, BK=64, 8 waves (2Mx4N), double-buffered LDS (128 KiB), 8-phase
// schedule with counted vmcnt (T3+T4) + setprio around MFMA clusters (T5).
// LDS swizzle: 3-bit XOR chunk swizzle (verified 0 bank conflicts on this problem),
// applied on the pre-swizzled global_load_lds SOURCE + on the ds_read side.
//
// Pipeline (per K-tile group of 4 phases, computing buffer c, tile t):
//   ph0: read all 8 B-frags + A-frag pair0; stage A(other,h0) <- t+1
//   ph1: A pair1;                            stage A(other,h1) <- t+1
//   ph2: A pair2;                            stage B(c,h0)     <- t+2
//   ph3: A pair3;                            stage B(c,h1)     <- t+2; vmcnt(4)
// Each phase: {ds_read; stage-issue; s_barrier; setprio(1); 16 MFMA; setprio(0); s_barrier}
// Region safety: every region restaged >=1 full barrier after its last read;
// vmcnt(4) at group end leaves only ph2/ph3's loads in flight, so everything the
// next group reads has landed. Accumulation order over K identical to old kernel.
constexpr int BM = 256, BN = 256, BK = 64;
constexpr int KT = DD / BK;                  // 32 K-tiles

__device__ inline void async_copy16(const void* g, void* l) {
  __builtin_amdgcn_global_load_lds(
      (const __attribute__((address_space(1))) unsigned int*)g,
      (__attribute__((address_space(3))) unsigned int*)l, 16, 0, 0);
}

// stage one 128x64 half-tile (16 KB): 2 global_load_lds x 512 threads x 16 B
__device__ __forceinline__ void stage_half(const unsigned short* src,
                                           unsigned short* dstRegion, int tid8) {
  async_copy16(src, dstRegion + tid8);                    // rows 0..63
  async_copy16(src + 64 * DD, dstRegion + 4096 + tid8);   // rows 64..127
}

__global__ void __launch_bounds__(512, 2) gemm_bt_kernel(
    const unsigned short* __restrict__ A,    // [M][K] bf16 bits (normalized x)
    const unsigned short* __restrict__ Bm,   // [N][K] bf16 bits (features)
    float* __restrict__ C) {                 // [M][N] fp32 sim
  // [buf][half][row 128][col 64] flattened; region = 8192 elems = 16 KB
  __shared__ __align__(16) unsigned short As[2 * 2 * 128 * 64];   // 64 KB
  __shared__ __align__(16) unsigned short Bs[2 * 2 * 128 * 64];   // 64 KB

  const int tid  = threadIdx.x;
  const int lane = tid & 63;
  const int wave = tid >> 6;      // 0..7
  const int l16  = lane & 15;
  const int quad = lane >> 4;
  const int rm   = wave >> 2;     // 0..1 : wave row-group (A half)
  const int rn   = wave & 3;      // 0..3 : wave col-group
  const int m0 = blockIdx.y * BM;
  const int n0 = blockIdx.x * BN;

  // ds_read chunk offsets: logical chunk (s*4+quad) xor'd by row&7 (=l16&7)
  const int xr = l16 & 7;
  const int cs[2] = { (quad ^ xr) * 8, ((4 + quad) ^ xr) * 8 };

  // staging geometry: thread covers linear LDS bytes tid*16 (+8192 for inst1);
  // physical chunk pc = tid&7 holds logical chunk pc^(row&7) -> pre-swizzled source
  const int srow = tid >> 3;                                  // 0..63
  const int lcol = ((tid & 7) ^ (srow & 7)) * 8;              // source col (elems)
  const int tid8 = tid * 8;
  const unsigned short* aSrcT = A  + (size_t)(m0 + srow) * DD + lcol;
  const unsigned short* bSrcT = Bm + (size_t)(n0 + srow) * DD + lcol;

  floatx4 acc[8][4] = {};

  // ---- prologue: A(buf0)<-tile0, B(buf0)<-tile0, B(buf1)<-tile1 ----
  stage_half(aSrcT,                As,          tid8);
  stage_half(aSrcT + 128 * DD,     As + 8192,   tid8);
  stage_half(bSrcT,                Bs,          tid8);
  stage_half(bSrcT + 128 * DD,     Bs + 8192,   tid8);
  stage_half(bSrcT + BK,           Bs + 16384,  tid8);
  stage_half(bSrcT + 128 * DD + BK, Bs + 24576, tid8);
  asm volatile("s_waitcnt vmcnt(4)" ::: "memory");   // tile-0 A+B landed
  asm volatile("s_barrier" ::: "memory");

  for (int t = 0; t < KT; ++t) {
    const int c = t & 1, o = c ^ 1;
    const unsigned short* aB = As + c * 16384 + rm * 8192 + l16 * 64;
    const unsigned short* bB = Bs + c * 16384 + (rn >> 1) * 8192
                                  + (rn & 1) * 4096 + l16 * 64;
    const int kA = (t + 1 < KT) ? (t + 1) * BK : 0;   // clamp: tail loads harmless
    const int kB = (t + 2 < KT) ? (t + 2) * BK : 0;
    const unsigned short* aS = aSrcT + kA;
    const unsigned short* bS = bSrcT + kB;

    const unsigned short* stSrc[4] = { aS, aS + 128 * DD, bS, bS + 128 * DD };
    unsigned short* stDst[4] = { As + o * 16384, As + o * 16384 + 8192,
                                 Bs + c * 16384, Bs + c * 16384 + 8192 };

    bf16x8 bf[4][2];
#pragma unroll
    for (int mp = 0; mp < 4; ++mp) {
      // ds-read register subtiles (phase 0: 12 reads; else 4)
      if (mp == 0) {
#pragma unroll
        for (int n = 0; n < 4; ++n)
#pragma unroll
          for (int s = 0; s < 2; ++s)
            bf[n][s] = __builtin_bit_cast(bf16x8,
                         *(const ushort8*)(bB + n * 1024 + cs[s]));
      }
      bf16x8 af[2][2];
#pragma unroll
      for (int mi = 0; mi < 2; ++mi)
#pragma unroll
        for (int s = 0; s < 2; ++s)
          af[mi][s] = __builtin_bit_cast(bf16x8,
                        *(const ushort8*)(aB + (mp * 2 + mi) * 1024 + cs[s]));

      // issue this phase's half-tile prefetch (stays in flight across barriers)
      stage_half(stSrc[mp], stDst[mp], tid8);

      asm volatile("s_barrier" ::: "memory");
      __builtin_amdgcn_s_setprio(1);
#pragma unroll
      for (int mi = 0; mi < 2; ++mi)
#pragma unroll
        for (int n = 0; n < 4; ++n)
#pragma unroll
          for (int s = 0; s < 2; ++s)
            acc[mp * 2 + mi][n] = __builtin_amdgcn_mfma_f32_16x16x32_bf16(
                af[mi][s], bf[n][s], acc[mp * 2 + mi][n], 0, 0, 0);
      __builtin_amdgcn_s_setprio(0);
      if (mp == 3)  // counted wait ONCE per K-tile: leave ph2/ph3 stages in flight
        asm volatile("s_waitcnt vmcnt(4)" ::: "memory");
      asm volatile("s_barrier" ::: "memory");
    }
  }

  // epilogue: C/D layout col = lane&15, row = quad*4 + reg  [m89/m91-verified]
#pragma unroll
  for (int r = 0; r < 8; ++r) {
    const int grow = m0 + rm * 128 + r * 16 + quad * 4;
#pragma unroll
    for (int n = 0; n < 4; ++n) {
      const int gcol = n0 + rn * 64 + n * 16 + l16;
#pragma unroll
      for (int i = 0; i < 4; ++i)
        C[(size_t)(grow + i) * NN + gcol] = acc[r][n][i];
    }
  }
}

// ---------------- K4: per-row CE terms from sim, single memory pass ----------------
__global__ void __launch_bounds__(256) rowstat_kernel(
    const float* __restrict__ sim, const int* __restrict__ tgt,
    float* __restrict__ ce_part) {
  __shared__ float sbuf[4];
  const int b = blockIdx.x;
  const float4* sr = (const float4*)(sim + (size_t)b * NN);
  constexpr float INV_T = 1.0f / TEMP;

  float4 dv[16];                       // 64 VGPRs of distances
  float m1 = -1e30f, s1 = 0.f;         // running LSE state for sim*INV_T
  float m2 = -1e30f;
#pragma unroll
  for (int i = 0; i < 16; ++i) {
    const int idx = i * 256 + threadIdx.x;   // NN/4 = 4096 float4s
    float4 s = sr[idx];
    float lm = fmaxf(fmaxf(s.x, s.y), fmaxf(s.z, s.w)) * INV_T;
    if (lm > m1) { s1 *= expf(m1 - lm); m1 = lm; }
    s1 += expf(s.x * INV_T - m1) + expf(s.y * INV_T - m1)
        + expf(s.z * INV_T - m1) + expf(s.w * INV_T - m1);
    float4 d;
    d.x = sqrtf(fmaxf(2.f - 2.f * s.x, 0.f));
    d.y = sqrtf(fmaxf(2.f - 2.f * s.y, 0.f));
    d.z = sqrtf(fmaxf(2.f - 2.f * s.z, 0.f));
    d.w = sqrtf(fmaxf(2.f - 2.f * s.w, 0.f));
    dv[i] = d;
    m2 = fmaxf(m2, fmaxf(fmaxf(d.x, d.y), fmaxf(d.z, d.w)));
  }
  const float M1 = block_max256(m1, sbuf);
  const float s1t = block_sum256(s1 * expf(m1 - M1), sbuf);
  const float M2 = block_max256(m2, sbuf);

  float s2 = 0.f;
#pragma unroll
  for (int i = 0; i < 16; ++i) {
    float4 d = dv[i];
    s2 += expf(d.x - M2) + expf(d.y - M2) + expf(d.z - M2) + expf(d.w - M2);
  }
  const float s2t = block_sum256(s2, sbuf);
  const float invs2 = 1.f / s2t;

  float sp = 0.f;
#pragma unroll
  for (int i = 0; i < 16; ++i) {
    float4 d = dv[i];
    sp += expf(expf(d.x - M2) * invs2) + expf(expf(d.y - M2) * invs2)
        + expf(expf(d.z - M2) * invs2) + expf(expf(d.w - M2) * invs2);
  }
  const float spt = block_sum256(sp, sbuf);

  if (threadIdx.x == 0) {
    const int t = tgt[b];
    const float st = sim[(size_t)b * NN + t];
    const float dt = sqrtf(fmaxf(2.f - 2.f * st, 0.f));
    const float pt = expf(dt - M2) * invs2;
    const float ce1 = M1 + logf(s1t) - st * INV_T;   // lse(sim/T) - sim_t/T
    const float ce2 = logf(spt) - pt;                // lse(p) - p_t
    ce_part[b] = ce1 + ce2;
  }
}

// ---------------- K5: final weighted reduce of all partials -> d_out ----------------
__global__ void __launch_bounds__(256) final_reduce_kernel(
    const float* __restrict__ mse_part,   // [3*BB]
    const float* __restrict__ ce_part,    // [3*BB]
    float* __restrict__ loss) {
  __shared__ float sbuf[4];
  float s = 0.f;
  for (int i = threadIdx.x; i < 3 * BB; i += 256) {
    const float w = (i < BB) ? (1.0f - LAMBDA2) : LAMBDA2;
    s += w * (MU * mse_part[i] + ce_part[i]);
  }
  s = block_sum256(s, sbuf);
  if (threadIdx.x == 0) loss[0] = s * (1.0f / (float)BB);
}

// ---------------- launch ----------------
extern "C" void kernel_launch(void* const* d_in, const int* in_sizes, int n_in,
                              void* d_out, int out_size, void* d_ws, size_t ws_size,
                              hipStream_t stream) {
  const float* xin[3] = {(const float*)d_in[0], (const float*)d_in[1], (const float*)d_in[2]};
  const float* tin[3] = {(const float*)d_in[3], (const float*)d_in[4], (const float*)d_in[5]};
  const int*   targets = (const int*)d_in[6];
  const float* fin[3] = {(const float*)d_in[8], (const float*)d_in[9], (const float*)d_in[10]};

  char* ws = (char*)d_ws;
  size_t off = 0;
  unsigned short* featb = (unsigned short*)(ws + off); off += (size_t)NN * DD * 2;  // 64 MiB
  float*          sim   = (float*)(ws + off);          off += (size_t)BB * NN * 4;  // 64 MiB
  unsigned short* xb    = (unsigned short*)(ws + off); off += (size_t)BB * DD * 2;  //  4 MiB
  float*          msep  = (float*)(ws + off);          off += (size_t)3 * BB * 4;
  float*          cep   = (float*)(ws + off);          off += (size_t)3 * BB * 4;

  for (int i = 0; i < 3; ++i) {
    norm_mse_kernel<<<BB, 256, 0, stream>>>(xin[i], tin[i], xb, msep + i * BB);
    feat_convert_kernel<<<4096, 256, 0, stream>>>(fin[i], featb);
    gemm_bt_kernel<<<dim3(NN / BN, BB / BM), 512, 0, stream>>>(xb, featb, sim);
    rowstat_kernel<<<BB, 256, 0, stream>>>(sim, targets, cep + i * BB);
  }
  final_reduce_kernel<<<1, 256, 0, stream>>>(msep, cep, (float*)d_out);
}

// Round 2
// 710.194 us; speedup vs baseline: 1.0602x; 1.0602x over previous
//
#include <hip/hip_runtime.h>

// ---------------- problem constants ----------------
constexpr int BB = 1024;      // batch
constexpr int DD = 2048;      // feature dim
constexpr int NN = 16384;     // memory entries
constexpr float TEMP   = 0.05f;
constexpr float LAMBDA2 = 0.5f;
constexpr float MU      = 1.0f;
constexpr float EPSN    = 1e-12f;

typedef __bf16  bf16x8  __attribute__((ext_vector_type(8)));
typedef unsigned short ushort8 __attribute__((ext_vector_type(8)));
typedef float   floatx4 __attribute__((ext_vector_type(4)));

__device__ inline unsigned short f32_to_bf16(float f) {
  unsigned int u = __builtin_bit_cast(unsigned int, f);
  u += 0x7fffu + ((u >> 16) & 1u);      // round-to-nearest-even
  return (unsigned short)(u >> 16);
}

__device__ inline float block_sum256(float v, float* sbuf) {
#pragma unroll
  for (int o = 32; o > 0; o >>= 1) v += __shfl_down(v, o, 64);
  int lane = threadIdx.x & 63, w = threadIdx.x >> 6;
  __syncthreads();
  if (lane == 0) sbuf[w] = v;
  __syncthreads();
  return sbuf[0] + sbuf[1] + sbuf[2] + sbuf[3];
}

__device__ inline float block_max256(float v, float* sbuf) {
#pragma unroll
  for (int o = 32; o > 0; o >>= 1) v = fmaxf(v, __shfl_down(v, o, 64));
  int lane = threadIdx.x & 63, w = threadIdx.x >> 6;
  __syncthreads();
  if (lane == 0) sbuf[w] = v;
  __syncthreads();
  return fmaxf(fmaxf(sbuf[0], sbuf[1]), fmaxf(sbuf[2], sbuf[3]));
}

// ---------------- K1: row-l2norm of student -> bf16, MSE vs normalized teacher ----
__global__ void __launch_bounds__(256) norm_mse_kernel(
    const float* __restrict__ X, const float* __restrict__ T,
    unsigned short* __restrict__ Xb, float* __restrict__ mse_part) {
  __shared__ float sbuf[4];
  const int b = blockIdx.x;
  const float4* xr = (const float4*)(X + (size_t)b * DD);
  const float4* tr = (const float4*)(T + (size_t)b * DD);
  float4 xv[2], tv[2];
  float sx = 0.f, st = 0.f;
#pragma unroll
  for (int i = 0; i < 2; ++i) {
    int idx = i * 256 + threadIdx.x;      // DD/4 = 512
    xv[i] = xr[idx];  tv[i] = tr[idx];
    sx += xv[i].x*xv[i].x + xv[i].y*xv[i].y + xv[i].z*xv[i].z + xv[i].w*xv[i].w;
    st += tv[i].x*tv[i].x + tv[i].y*tv[i].y + tv[i].z*tv[i].z + tv[i].w*tv[i].w;
  }
  sx = block_sum256(sx, sbuf);
  st = block_sum256(st, sbuf);
  const float rx = 1.f / fmaxf(sqrtf(sx), EPSN);
  const float rt = 1.f / fmaxf(sqrtf(st), EPSN);
  float ms = 0.f;
  ushort4* xb4 = (ushort4*)(Xb + (size_t)b * DD);
#pragma unroll
  for (int i = 0; i < 2; ++i) {
    int idx = i * 256 + threadIdx.x;
    float xn, tn, d;
    ushort4 o;
    xn = xv[i].x * rx; tn = tv[i].x * rt; d = xn - tn; ms += d * d; o.x = f32_to_bf16(xn);
    xn = xv[i].y * rx; tn = tv[i].y * rt; d = xn - tn; ms += d * d; o.y = f32_to_bf16(xn);
    xn = xv[i].z * rx; tn = tv[i].z * rt; d = xn - tn; ms += d * d; o.z = f32_to_bf16(xn);
    xn = xv[i].w * rx; tn = tv[i].w * rt; d = xn - tn; ms += d * d; o.w = f32_to_bf16(xn);
    xb4[idx] = o;
  }
  ms = block_sum256(ms, sbuf);
  if (threadIdx.x == 0) mse_part[b] = ms;
}

// ---------------- K2: features fp32 -> bf16, pure streaming convert ----------------
__global__ void __launch_bounds__(256) feat_convert_kernel(
    const float* __restrict__ F, unsigned short* __restrict__ Fb) {
  const int stride = gridDim.x * 256;
  const float4* fr = (const float4*)F;
  constexpr int TOT = NN * DD / 8;            // ushort8 chunks
  for (int i = blockIdx.x * 256 + threadIdx.x; i < TOT; i += stride) {
    float4 a = fr[i * 2], b = fr[i * 2 + 1];
    ushort8 o;
    o[0] = f32_to_bf16(a.x); o[1] = f32_to_bf16(a.y);
    o[2] = f32_to_bf16(a.z); o[3] = f32_to_bf16(a.w);
    o[4] = f32_to_bf16(b.x); o[5] = f32_to_bf16(b.y);
    o[6] = f32_to_bf16(b.z); o[7] = f32_to_bf16(b.w);
    *(ushort8*)(Fb + (size_t)i * 8) = o;
  }
}

// ---------------- K3: bf16 MFMA GEMM  sim[M,N] = A[M,K] * Bm[N,K]^T ---------------
// 256x256 tile, BK=64, 8 waves (2Mx4N), double-buffered LDS (128 KiB).
// Round-2 restructure: 2 K-tiles per iteration with COMPILE-TIME buffer indices
// (full unroll of h=0/1), so LDS reads (buf h) and global_load_lds writes
// (buf h^1) are provably disjoint -> the memory legalizer cannot insert
// alias-conservative drains that defeated the round-1 counted-vmcnt schedule.
// One vmcnt(0)+s_barrier per K-tile, NO intra-tile barriers: within a half,
// reads and DMA-writes never conflict, so LDS service overlaps MFMA freely.
//
// Race audit:
//  - buf(h^1) DMA-written in half h; its last readers finished in the previous
//    half (frag reads complete before each wave's MFMA -> barrier arrive).
//  - buf(h) read in half h; its DMA-writes were issued last half by each wave,
//    and each wave did vmcnt(0) BEFORE arriving at the barrier -> barrier exit
//    implies all waves' loads landed.
// Accumulation order over K identical to previous versions.
constexpr int BM = 256, BN = 256, BK = 64;
constexpr int KT = DD / BK;                  // 32 K-tiles

__device__ inline void async_copy16(const void* g, void* l) {
  __builtin_amdgcn_global_load_lds(
      (const __attribute__((address_space(1))) unsigned int*)g,
      (__attribute__((address_space(3))) unsigned int*)l, 16, 0, 0);
}

// stage one 128x64 half-tile (16 KB): 2 global_load_lds x 512 threads x 16 B
__device__ __forceinline__ void stage_half(const unsigned short* src,
                                           unsigned short* dstRegion, int tid8) {
  async_copy16(src, dstRegion + tid8);                    // rows 0..63
  async_copy16(src + 64 * DD, dstRegion + 4096 + tid8);   // rows 64..127
}

__global__ void __launch_bounds__(512, 2) gemm_bt_kernel(
    const unsigned short* __restrict__ A,    // [M][K] bf16 bits (normalized x)
    const unsigned short* __restrict__ Bm,   // [N][K] bf16 bits (features)
    float* __restrict__ C) {                 // [M][N] fp32 sim
  // [buf][half][row 128][col 64] flattened; buffer = 16384 elems = 32 KB
  __shared__ __align__(16) unsigned short As[2 * 2 * 128 * 64];   // 64 KB
  __shared__ __align__(16) unsigned short Bs[2 * 2 * 128 * 64];   // 64 KB

  const int tid  = threadIdx.x;
  const int lane = tid & 63;
  const int wave = tid >> 6;      // 0..7
  const int l16  = lane & 15;
  const int quad = lane >> 4;
  const int rm   = wave >> 2;     // 0..1 : wave row-group (A half)
  const int rn   = wave & 3;      // 0..3 : wave col-group
  const int m0 = blockIdx.y * BM;
  const int n0 = blockIdx.x * BN;

  // ds_read chunk offsets: logical chunk (s*4+quad) xor'd by row&7 (=l16&7)
  const int xr = l16 & 7;
  const int cs[2] = { (quad ^ xr) * 8, ((4 + quad) ^ xr) * 8 };

  // staging geometry: thread covers linear LDS bytes tid*16 (+8192 B for inst1);
  // physical chunk pc = tid&7 holds logical chunk pc^(row&7) -> pre-swizzled source
  const int srow = tid >> 3;                                  // 0..63
  const int lcol = ((tid & 7) ^ (srow & 7)) * 8;              // source col (elems)
  const int tid8 = tid * 8;
  const unsigned short* aSrcT = A  + (size_t)(m0 + srow) * DD + lcol;
  const unsigned short* bSrcT = Bm + (size_t)(n0 + srow) * DD + lcol;

  floatx4 acc[8][4] = {};

  // ---- prologue: tile 0 -> buf0 ----
  stage_half(aSrcT,            As,        tid8);
  stage_half(aSrcT + 128 * DD, As + 8192, tid8);
  stage_half(bSrcT,            Bs,        tid8);
  stage_half(bSrcT + 128 * DD, Bs + 8192, tid8);
  asm volatile("s_waitcnt vmcnt(0)" ::: "memory");
  asm volatile("s_barrier" ::: "memory");

  for (int i = 0; i < KT / 2; ++i) {
#pragma unroll
    for (int h = 0; h < 2; ++h) {          // fully unrolled: h is a constant
      const int ob = h ^ 1;
      // half h computes tile 2i+h from buf h; stages tile 2i+h+1 into buf h^1
      const int kst = (h == 0) ? (2 * i + 1) : ((2 * i + 2) & (KT - 1)); // tail clamp
      const unsigned short* aS = aSrcT + kst * BK;
      const unsigned short* bS = bSrcT + kst * BK;
      // issue stages FIRST: ~2 k-steps of slack before the vmcnt at half end
      stage_half(aS,            As + ob * 16384,        tid8);
      stage_half(aS + 128 * DD, As + ob * 16384 + 8192, tid8);
      stage_half(bS,            Bs + ob * 16384,        tid8);
      stage_half(bS + 128 * DD, Bs + ob * 16384 + 8192, tid8);

      const unsigned short* aB = As + h * 16384 + rm * 8192 + l16 * 64;
      const unsigned short* bB = Bs + h * 16384 + (rn >> 1) * 8192
                                    + (rn & 1) * 4096 + l16 * 64;
#pragma unroll
      for (int s = 0; s < 2; ++s) {        // two k-steps of 32; deps 32 apart
        bf16x8 bf[4], af[8];
#pragma unroll
        for (int n = 0; n < 4; ++n)
          bf[n] = __builtin_bit_cast(bf16x8, *(const ushort8*)(bB + n * 1024 + cs[s]));
#pragma unroll
        for (int r = 0; r < 8; ++r)
          af[r] = __builtin_bit_cast(bf16x8, *(const ushort8*)(aB + r * 1024 + cs[s]));
        __builtin_amdgcn_s_setprio(1);
#pragma unroll
        for (int r = 0; r < 8; ++r)
#pragma unroll
          for (int n = 0; n < 4; ++n)
            acc[r][n] = __builtin_amdgcn_mfma_f32_16x16x32_bf16(
                af[r], bf[n], acc[r][n], 0, 0, 0);
        __builtin_amdgcn_s_setprio(0);
      }
      // per-wave: my stages landed; then barrier: ALL waves' stages landed
      asm volatile("s_waitcnt vmcnt(0)" ::: "memory");
      asm volatile("s_barrier" ::: "memory");
    }
  }

  // epilogue: C/D layout col = lane&15, row = quad*4 + reg  [m89/m91-verified]
#pragma unroll
  for (int r = 0; r < 8; ++r) {
    const int grow = m0 + rm * 128 + r * 16 + quad * 4;
#pragma unroll
    for (int n = 0; n < 4; ++n) {
      const int gcol = n0 + rn * 64 + n * 16 + l16;
#pragma unroll
      for (int i = 0; i < 4; ++i)
        C[(size_t)(grow + i) * NN + gcol] = acc[r][n][i];
    }
  }
}

// ---------------- K4: per-row CE terms from sim, single memory pass ----------------
__global__ void __launch_bounds__(256) rowstat_kernel(
    const float* __restrict__ sim, const int* __restrict__ tgt,
    float* __restrict__ ce_part) {
  __shared__ float sbuf[4];
  const int b = blockIdx.x;
  const float4* sr = (const float4*)(sim + (size_t)b * NN);
  constexpr float INV_T = 1.0f / TEMP;

  float4 dv[16];                       // 64 VGPRs of distances
  float m1 = -1e30f, s1 = 0.f;         // running LSE state for sim*INV_T
  float m2 = -1e30f;
#pragma unroll
  for (int i = 0; i < 16; ++i) {
    const int idx = i * 256 + threadIdx.x;   // NN/4 = 4096 float4s
    float4 s = sr[idx];
    float lm = fmaxf(fmaxf(s.x, s.y), fmaxf(s.z, s.w)) * INV_T;
    if (lm > m1) { s1 *= expf(m1 - lm); m1 = lm; }
    s1 += expf(s.x * INV_T - m1) + expf(s.y * INV_T - m1)
        + expf(s.z * INV_T - m1) + expf(s.w * INV_T - m1);
    float4 d;
    d.x = sqrtf(fmaxf(2.f - 2.f * s.x, 0.f));
    d.y = sqrtf(fmaxf(2.f - 2.f * s.y, 0.f));
    d.z = sqrtf(fmaxf(2.f - 2.f * s.z, 0.f));
    d.w = sqrtf(fmaxf(2.f - 2.f * s.w, 0.f));
    dv[i] = d;
    m2 = fmaxf(m2, fmaxf(fmaxf(d.x, d.y), fmaxf(d.z, d.w)));
  }
  const float M1 = block_max256(m1, sbuf);
  const float s1t = block_sum256(s1 * expf(m1 - M1), sbuf);
  const float M2 = block_max256(m2, sbuf);

  float s2 = 0.f;
#pragma unroll
  for (int i = 0; i < 16; ++i) {
    float4 d = dv[i];
    s2 += expf(d.x - M2) + expf(d.y - M2) + expf(d.z - M2) + expf(d.w - M2);
  }
  const float s2t = block_sum256(s2, sbuf);
  const float invs2 = 1.f / s2t;

  float sp = 0.f;
#pragma unroll
  for (int i = 0; i < 16; ++i) {
    float4 d = dv[i];
    sp += expf(expf(d.x - M2) * invs2) + expf(expf(d.y - M2) * invs2)
        + expf(expf(d.z - M2) * invs2) + expf(expf(d.w - M2) * invs2);
  }
  const float spt = block_sum256(sp, sbuf);

  if (threadIdx.x == 0) {
    const int t = tgt[b];
    const float st = sim[(size_t)b * NN + t];
    const float dt = sqrtf(fmaxf(2.f - 2.f * st, 0.f));
    const float pt = expf(dt - M2) * invs2;
    const float ce1 = M1 + logf(s1t) - st * INV_T;   // lse(sim/T) - sim_t/T
    const float ce2 = logf(spt) - pt;                // lse(p) - p_t
    ce_part[b] = ce1 + ce2;
  }
}

// ---------------- K5: final weighted reduce of all partials -> d_out ----------------
__global__ void __launch_bounds__(256) final_reduce_kernel(
    const float* __restrict__ mse_part,   // [3*BB]
    const float* __restrict__ ce_part,    // [3*BB]
    float* __restrict__ loss) {
  __shared__ float sbuf[4];
  float s = 0.f;
  for (int i = threadIdx.x; i < 3 * BB; i += 256) {
    const float w = (i < BB) ? (1.0f - LAMBDA2) : LAMBDA2;
    s += w * (MU * mse_part[i] + ce_part[i]);
  }
  s = block_sum256(s, sbuf);
  if (threadIdx.x == 0) loss[0] = s * (1.0f / (float)BB);
}

// ---------------- launch ----------------
extern "C" void kernel_launch(void* const* d_in, const int* in_sizes, int n_in,
                              void* d_out, int out_size, void* d_ws, size_t ws_size,
                              hipStream_t stream) {
  const float* xin[3] = {(const float*)d_in[0], (const float*)d_in[1], (const float*)d_in[2]};
  const float* tin[3] = {(const float*)d_in[3], (const float*)d_in[4], (const float*)d_in[5]};
  const int*   targets = (const int*)d_in[6];
  const float* fin[3] = {(const float*)d_in[8], (const float*)d_in[9], (const float*)d_in[10]};

  char* ws = (char*)d_ws;
  size_t off = 0;
  unsigned short* featb = (unsigned short*)(ws + off); off += (size_t)NN * DD * 2;  // 64 MiB
  float*          sim   = (float*)(ws + off);          off += (size_t)BB * NN * 4;  // 64 MiB
  unsigned short* xb    = (unsigned short*)(ws + off); off += (size_t)BB * DD * 2;  //  4 MiB
  float*          msep  = (float*)(ws + off);          off += (size_t)3 * BB * 4;
  float*          cep   = (float*)(ws + off);          off += (size_t)3 * BB * 4;

  for (int i = 0; i < 3; ++i) {
    norm_mse_kernel<<<BB, 256, 0, stream>>>(xin[i], tin[i], xb, msep + i * BB);
    feat_convert_kernel<<<4096, 256, 0, stream>>>(fin[i], featb);
    gemm_bt_kernel<<<dim3(NN / BN, BB / BM), 512, 0, stream>>>(xb, featb, sim);
    rowstat_kernel<<<BB, 256, 0, stream>>>(sim, targets, cep + i * BB);
  }
  final_reduce_kernel<<<1, 256, 0, stream>>>(msep, cep, (float*)d_out);
}

// Round 3
// 697.332 us; speedup vs baseline: 1.0797x; 1.0184x over previous
//
#include <hip/hip_runtime.h>

// ---------------- problem constants ----------------
constexpr int BB = 1024;      // batch
constexpr int DD = 2048;      // feature dim
constexpr int NN = 16384;     // memory entries
constexpr float TEMP   = 0.05f;
constexpr float LAMBDA2 = 0.5f;
constexpr float MU      = 1.0f;
constexpr float EPSN    = 1e-12f;

typedef __bf16  bf16x8  __attribute__((ext_vector_type(8)));
typedef unsigned short ushort8 __attribute__((ext_vector_type(8)));
typedef float   floatx4 __attribute__((ext_vector_type(4)));

__device__ inline unsigned short f32_to_bf16(float f) {
  unsigned int u = __builtin_bit_cast(unsigned int, f);
  u += 0x7fffu + ((u >> 16) & 1u);      // round-to-nearest-even
  return (unsigned short)(u >> 16);
}

__device__ inline float block_sum256(float v, float* sbuf) {
#pragma unroll
  for (int o = 32; o > 0; o >>= 1) v += __shfl_down(v, o, 64);
  int lane = threadIdx.x & 63, w = threadIdx.x >> 6;
  __syncthreads();
  if (lane == 0) sbuf[w] = v;
  __syncthreads();
  return sbuf[0] + sbuf[1] + sbuf[2] + sbuf[3];
}

__device__ inline float block_max256(float v, float* sbuf) {
#pragma unroll
  for (int o = 32; o > 0; o >>= 1) v = fmaxf(v, __shfl_down(v, o, 64));
  int lane = threadIdx.x & 63, w = threadIdx.x >> 6;
  __syncthreads();
  if (lane == 0) sbuf[w] = v;
  __syncthreads();
  return fmaxf(fmaxf(sbuf[0], sbuf[1]), fmaxf(sbuf[2], sbuf[3]));
}

// ---------------- K1: row-l2norm of student -> bf16, MSE vs normalized teacher ----
__global__ void __launch_bounds__(256) norm_mse_kernel(
    const float* __restrict__ X, const float* __restrict__ T,
    unsigned short* __restrict__ Xb, float* __restrict__ mse_part) {
  __shared__ float sbuf[4];
  const int b = blockIdx.x;
  const float4* xr = (const float4*)(X + (size_t)b * DD);
  const float4* tr = (const float4*)(T + (size_t)b * DD);
  float4 xv[2], tv[2];
  float sx = 0.f, st = 0.f;
#pragma unroll
  for (int i = 0; i < 2; ++i) {
    int idx = i * 256 + threadIdx.x;      // DD/4 = 512
    xv[i] = xr[idx];  tv[i] = tr[idx];
    sx += xv[i].x*xv[i].x + xv[i].y*xv[i].y + xv[i].z*xv[i].z + xv[i].w*xv[i].w;
    st += tv[i].x*tv[i].x + tv[i].y*tv[i].y + tv[i].z*tv[i].z + tv[i].w*tv[i].w;
  }
  sx = block_sum256(sx, sbuf);
  st = block_sum256(st, sbuf);
  const float rx = 1.f / fmaxf(sqrtf(sx), EPSN);
  const float rt = 1.f / fmaxf(sqrtf(st), EPSN);
  float ms = 0.f;
  ushort4* xb4 = (ushort4*)(Xb + (size_t)b * DD);
#pragma unroll
  for (int i = 0; i < 2; ++i) {
    int idx = i * 256 + threadIdx.x;
    float xn, tn, d;
    ushort4 o;
    xn = xv[i].x * rx; tn = tv[i].x * rt; d = xn - tn; ms += d * d; o.x = f32_to_bf16(xn);
    xn = xv[i].y * rx; tn = tv[i].y * rt; d = xn - tn; ms += d * d; o.y = f32_to_bf16(xn);
    xn = xv[i].z * rx; tn = tv[i].z * rt; d = xn - tn; ms += d * d; o.z = f32_to_bf16(xn);
    xn = xv[i].w * rx; tn = tv[i].w * rt; d = xn - tn; ms += d * d; o.w = f32_to_bf16(xn);
    xb4[idx] = o;
  }
  ms = block_sum256(ms, sbuf);
  if (threadIdx.x == 0) mse_part[b] = ms;
}

// ---------------- K2: features fp32 -> bf16, pure streaming convert ----------------
__global__ void __launch_bounds__(256) feat_convert_kernel(
    const float* __restrict__ F, unsigned short* __restrict__ Fb) {
  const int stride = gridDim.x * 256;
  const float4* fr = (const float4*)F;
  constexpr int TOT = NN * DD / 8;            // ushort8 chunks
  for (int i = blockIdx.x * 256 + threadIdx.x; i < TOT; i += stride) {
    float4 a = fr[i * 2], b = fr[i * 2 + 1];
    ushort8 o;
    o[0] = f32_to_bf16(a.x); o[1] = f32_to_bf16(a.y);
    o[2] = f32_to_bf16(a.z); o[3] = f32_to_bf16(a.w);
    o[4] = f32_to_bf16(b.x); o[5] = f32_to_bf16(b.y);
    o[6] = f32_to_bf16(b.z); o[7] = f32_to_bf16(b.w);
    *(ushort8*)(Fb + (size_t)i * 8) = o;
  }
}

// ---------------- K3: bf16 MFMA GEMM  sim[M,N] = A[M,K] * Bm[N,K]^T ---------------
// 256x256 tile, BK=64, 8 waves (2Mx4N), double-buffered LDS (128 KiB).
// Round-3: full m201-style 8-phase schedule = the untested combination of
//   (a) COMPILE-TIME buffer indices (h=0/1 unrolled; round-0's flaw fixed) and
//   (b) counted vmcnt(4) once per K-tile, NEVER vmcnt(0) (round-2's flaw fixed).
// Per K-tile (4 phases): ph0 reads all 8 B-frags + A pair0 and stages
// A(t+1)h0 -> buf(h^1); ph1/ph2/ph3 read A pairs 1/2/3 and stage
// A(t+1)h1 -> buf(h^1), B(t+2)h0/h1 -> buf(h) (B region of buf(h) is dead
// after ph0 reads). Each phase: {ds_read; stage; s_barrier; lgkmcnt(0);
// setprio(1); 16 MFMA; setprio(0); [ph3: vmcnt(4)]; s_barrier}.
//
// In-flight audit (per thread, steady state): at tile t's vmcnt(4):
// outstanding = B(t+1) 4 + A(t+1) 4 + B(t+2) 4 = 12 -> wait to 4 leaves only
// B(t+2); guarantees A(t+1) (slack ~3 phases) and B(t+1) (slack ~1.5 tiles)
// landed = exactly what tile t+1 reads. DMA latency never exposed.
// Race audit: stages target regions whose last readers completed >= 1 barrier
// earlier (A(t+1): last read tile t-1, re-staged tile t ph0 after tile t-1's
// final barrier + per-wave lgkmcnt(0); B(t+2): buf(h) B-region read ph0,
// staged ph2 -- wave reaches ph2 only after ALL waves passed ph0's post-MFMA
// barrier, and each waited lgkmcnt(0) before it). Accumulation order per
// accumulator identical to rounds 0-2 -> bitwise-identical C.
constexpr int BM = 256, BN = 256, BK = 64;
constexpr int KT = DD / BK;                  // 32 K-tiles

__device__ inline void async_copy16(const void* g, void* l) {
  __builtin_amdgcn_global_load_lds(
      (const __attribute__((address_space(1))) unsigned int*)g,
      (__attribute__((address_space(3))) unsigned int*)l, 16, 0, 0);
}

// stage one 128x64 half-tile (16 KB): 2 global_load_lds x 512 threads x 16 B
__device__ __forceinline__ void stage_half(const unsigned short* src,
                                           unsigned short* dstRegion, int tid8) {
  async_copy16(src, dstRegion + tid8);                    // rows 0..63
  async_copy16(src + 64 * DD, dstRegion + 4096 + tid8);   // rows 64..127
}

__global__ void __launch_bounds__(512, 2) gemm_bt_kernel(
    const unsigned short* __restrict__ A,    // [M][K] bf16 bits (normalized x)
    const unsigned short* __restrict__ Bm,   // [N][K] bf16 bits (features)
    float* __restrict__ C) {                 // [M][N] fp32 sim
  // [buf][half][row 128][col 64] flattened; buffer = 16384 elems = 32 KB
  __shared__ __align__(16) unsigned short As[2 * 2 * 128 * 64];   // 64 KB
  __shared__ __align__(16) unsigned short Bs[2 * 2 * 128 * 64];   // 64 KB

  const int tid  = threadIdx.x;
  const int lane = tid & 63;
  const int wave = tid >> 6;      // 0..7
  const int l16  = lane & 15;
  const int quad = lane >> 4;
  const int rm   = wave >> 2;     // 0..1 : wave row-group (A half)
  const int rn   = wave & 3;      // 0..3 : wave col-group
  const int m0 = blockIdx.y * BM;
  const int n0 = blockIdx.x * BN;

  // ds_read chunk offsets: logical chunk (s*4+quad) xor'd by row&7 (=l16&7)
  const int xr = l16 & 7;
  const int cs[2] = { (quad ^ xr) * 8, ((4 + quad) ^ xr) * 8 };

  // staging geometry: thread covers linear LDS bytes tid*16 (+8192 B for inst1);
  // physical chunk pc = tid&7 holds logical chunk pc^(row&7) -> pre-swizzled source
  const int srow = tid >> 3;                                  // 0..63
  const int lcol = ((tid & 7) ^ (srow & 7)) * 8;              // source col (elems)
  const int tid8 = tid * 8;
  const unsigned short* aSrcT = A  + (size_t)(m0 + srow) * DD + lcol;
  const unsigned short* bSrcT = Bm + (size_t)(n0 + srow) * DD + lcol;

  floatx4 acc[8][4] = {};

  // ---- prologue: A(0)->As0, B(0)->Bs0, B(1)->Bs1; wait A(0)+B(0) ----
  stage_half(aSrcT,                 As,         tid8);
  stage_half(aSrcT + 128 * DD,      As + 8192,  tid8);
  stage_half(bSrcT,                 Bs,         tid8);
  stage_half(bSrcT + 128 * DD,      Bs + 8192,  tid8);
  stage_half(bSrcT + BK,            Bs + 16384, tid8);
  stage_half(bSrcT + 128 * DD + BK, Bs + 24576, tid8);
  asm volatile("s_waitcnt vmcnt(4)" ::: "memory");   // leaves B(1) in flight
  asm volatile("s_barrier" ::: "memory");

  for (int i = 0; i < KT / 2; ++i) {
#pragma unroll
    for (int h = 0; h < 2; ++h) {          // fully unrolled: h is a constant
      const int t = 2 * i + h;
      unsigned short* Adst = As + (h ^ 1) * 16384;   // A(t+1) -> other buffer
      unsigned short* Bdst = Bs + h * 16384;         // B(t+2) -> own buffer
      const int kA = (t + 1 < KT) ? (t + 1) * BK : 0;   // tail clamp: junk loads
      const int kB = (t + 2 < KT) ? (t + 2) * BK : 0;   // into dead regions
      const unsigned short* aS = aSrcT + kA;
      const unsigned short* bS = bSrcT + kB;
      const unsigned short* aB = As + h * 16384 + rm * 8192 + l16 * 64;
      const unsigned short* bB = Bs + h * 16384 + rn * 4096 + l16 * 64;

      bf16x8 bf[4][2];
#pragma unroll
      for (int mp = 0; mp < 4; ++mp) {     // 4 phases per K-tile
        if (mp == 0) {
#pragma unroll
          for (int n = 0; n < 4; ++n)
#pragma unroll
            for (int s = 0; s < 2; ++s)
              bf[n][s] = __builtin_bit_cast(bf16x8,
                           *(const ushort8*)(bB + n * 1024 + cs[s]));
        }
        bf16x8 af[2][2];
#pragma unroll
        for (int mi = 0; mi < 2; ++mi)
#pragma unroll
          for (int s = 0; s < 2; ++s)
            af[mi][s] = __builtin_bit_cast(bf16x8,
                          *(const ushort8*)(aB + (mp * 2 + mi) * 1024 + cs[s]));

        // one half-tile prefetch per phase (stays in flight across barriers)
        if      (mp == 0) stage_half(aS,            Adst,        tid8);
        else if (mp == 1) stage_half(aS + 128 * DD, Adst + 8192, tid8);
        else if (mp == 2) stage_half(bS,            Bdst,        tid8);
        else              stage_half(bS + 128 * DD, Bdst + 8192, tid8);

        asm volatile("s_barrier" ::: "memory");
        asm volatile("s_waitcnt lgkmcnt(0)" ::: "memory");
        __builtin_amdgcn_s_setprio(1);
#pragma unroll
        for (int mi = 0; mi < 2; ++mi)
#pragma unroll
          for (int n = 0; n < 4; ++n)
#pragma unroll
            for (int s = 0; s < 2; ++s)
              acc[mp * 2 + mi][n] = __builtin_amdgcn_mfma_f32_16x16x32_bf16(
                  af[mi][s], bf[n][s], acc[mp * 2 + mi][n], 0, 0, 0);
        __builtin_amdgcn_s_setprio(0);
        if (mp == 3)   // counted wait ONCE per K-tile; never drain to 0
          asm volatile("s_waitcnt vmcnt(4)" ::: "memory");
        asm volatile("s_barrier" ::: "memory");
      }
    }
  }

  // epilogue: C/D layout col = lane&15, row = quad*4 + reg  [m89/m91-verified]
#pragma unroll
  for (int r = 0; r < 8; ++r) {
    const int grow = m0 + rm * 128 + r * 16 + quad * 4;
#pragma unroll
    for (int n = 0; n < 4; ++n) {
      const int gcol = n0 + rn * 64 + n * 16 + l16;
#pragma unroll
      for (int i = 0; i < 4; ++i)
        C[(size_t)(grow + i) * NN + gcol] = acc[r][n][i];
    }
  }
}

// ---------------- K4: per-row CE terms from sim, single memory pass ----------------
__global__ void __launch_bounds__(256) rowstat_kernel(
    const float* __restrict__ sim, const int* __restrict__ tgt,
    float* __restrict__ ce_part) {
  __shared__ float sbuf[4];
  const int b = blockIdx.x;
  const float4* sr = (const float4*)(sim + (size_t)b * NN);
  constexpr float INV_T = 1.0f / TEMP;

  float4 dv[16];                       // 64 VGPRs of distances
  float m1 = -1e30f, s1 = 0.f;         // running LSE state for sim*INV_T
  float m2 = -1e30f;
#pragma unroll
  for (int i = 0; i < 16; ++i) {
    const int idx = i * 256 + threadIdx.x;   // NN/4 = 4096 float4s
    float4 s = sr[idx];
    float lm = fmaxf(fmaxf(s.x, s.y), fmaxf(s.z, s.w)) * INV_T;
    if (lm > m1) { s1 *= expf(m1 - lm); m1 = lm; }
    s1 += expf(s.x * INV_T - m1) + expf(s.y * INV_T - m1)
        + expf(s.z * INV_T - m1) + expf(s.w * INV_T - m1);
    float4 d;
    d.x = sqrtf(fmaxf(2.f - 2.f * s.x, 0.f));
    d.y = sqrtf(fmaxf(2.f - 2.f * s.y, 0.f));
    d.z = sqrtf(fmaxf(2.f - 2.f * s.z, 0.f));
    d.w = sqrtf(fmaxf(2.f - 2.f * s.w, 0.f));
    dv[i] = d;
    m2 = fmaxf(m2, fmaxf(fmaxf(d.x, d.y), fmaxf(d.z, d.w)));
  }
  const float M1 = block_max256(m1, sbuf);
  const float s1t = block_sum256(s1 * expf(m1 - M1), sbuf);
  const float M2 = block_max256(m2, sbuf);

  float s2 = 0.f;
#pragma unroll
  for (int i = 0; i < 16; ++i) {
    float4 d = dv[i];
    s2 += expf(d.x - M2) + expf(d.y - M2) + expf(d.z - M2) + expf(d.w - M2);
  }
  const float s2t = block_sum256(s2, sbuf);
  const float invs2 = 1.f / s2t;

  float sp = 0.f;
#pragma unroll
  for (int i = 0; i < 16; ++i) {
    float4 d = dv[i];
    sp += expf(expf(d.x - M2) * invs2) + expf(expf(d.y - M2) * invs2)
        + expf(expf(d.z - M2) * invs2) + expf(expf(d.w - M2) * invs2);
  }
  const float spt = block_sum256(sp, sbuf);

  if (threadIdx.x == 0) {
    const int t = tgt[b];
    const float st = sim[(size_t)b * NN + t];
    const float dt = sqrtf(fmaxf(2.f - 2.f * st, 0.f));
    const float pt = expf(dt - M2) * invs2;
    const float ce1 = M1 + logf(s1t) - st * INV_T;   // lse(sim/T) - sim_t/T
    const float ce2 = logf(spt) - pt;                // lse(p) - p_t
    ce_part[b] = ce1 + ce2;
  }
}

// ---------------- K5: final weighted reduce of all partials -> d_out ----------------
__global__ void __launch_bounds__(256) final_reduce_kernel(
    const float* __restrict__ mse_part,   // [3*BB]
    const float* __restrict__ ce_part,    // [3*BB]
    float* __restrict__ loss) {
  __shared__ float sbuf[4];
  float s = 0.f;
  for (int i = threadIdx.x; i < 3 * BB; i += 256) {
    const float w = (i < BB) ? (1.0f - LAMBDA2) : LAMBDA2;
    s += w * (MU * mse_part[i] + ce_part[i]);
  }
  s = block_sum256(s, sbuf);
  if (threadIdx.x == 0) loss[0] = s * (1.0f / (float)BB);
}

// ---------------- launch ----------------
extern "C" void kernel_launch(void* const* d_in, const int* in_sizes, int n_in,
                              void* d_out, int out_size, void* d_ws, size_t ws_size,
                              hipStream_t stream) {
  const float* xin[3] = {(const float*)d_in[0], (const float*)d_in[1], (const float*)d_in[2]};
  const float* tin[3] = {(const float*)d_in[3], (const float*)d_in[4], (const float*)d_in[5]};
  const int*   targets = (const int*)d_in[6];
  const float* fin[3] = {(const float*)d_in[8], (const float*)d_in[9], (const float*)d_in[10]};

  char* ws = (char*)d_ws;
  size_t off = 0;
  unsigned short* featb = (unsigned short*)(ws + off); off += (size_t)NN * DD * 2;  // 64 MiB
  float*          sim   = (float*)(ws + off);          off += (size_t)BB * NN * 4;  // 64 MiB
  unsigned short* xb    = (unsigned short*)(ws + off); off += (size_t)BB * DD * 2;  //  4 MiB
  float*          msep  = (float*)(ws + off);          off += (size_t)3 * BB * 4;
  float*          cep   = (float*)(ws + off);          off += (size_t)3 * BB * 4;

  for (int i = 0; i < 3; ++i) {
    norm_mse_kernel<<<BB, 256, 0, stream>>>(xin[i], tin[i], xb, msep + i * BB);
    feat_convert_kernel<<<4096, 256, 0, stream>>>(fin[i], featb);
    gemm_bt_kernel<<<dim3(NN / BN, BB / BM), 512, 0, stream>>>(xb, featb, sim);
    rowstat_kernel<<<BB, 256, 0, stream>>>(sim, targets, cep + i * BB);
  }
  final_reduce_kernel<<<1, 256, 0, stream>>>(msep, cep, (float*)d_out);
}